// Round 7
// baseline (431.401 us; speedup 1.0000x reference)
//
#include <hip/hip_runtime.h>
#include <hip/hip_bf16.h>

typedef unsigned short ushort_t;
typedef __attribute__((ext_vector_type(8))) short short8;   // 8 x bf16 (4 VGPRs)
typedef __attribute__((ext_vector_type(4))) float floatx4;  // MFMA acc

#define BATCH 4
#define SEQ   2048
#define CH    1024
#define NHEAD 16
#define HSZ   64
#define MROWS (BATCH * SEQ)  // 8192

// async global->LDS, 16B per lane; LDS dest = wave-uniform base + lane*16
#define GLD16(gptr, lptr) \
    __builtin_amdgcn_global_load_lds((const __attribute__((address_space(1))) unsigned int*)(gptr), \
                                     (__attribute__((address_space(3))) unsigned int*)(lptr), 16, 0, 0)

__device__ inline ushort_t f2b(float f) {
    __hip_bfloat16 h = __float2bfloat16(f);
    return *(ushort_t*)&h;
}
__device__ inline float b2f(ushort_t u) {
    return __bfloat162float(*(__hip_bfloat16*)&u);
}

// -------- dtype detect (parallel): *flag = 1 if x is bf16, 0 if f32 --------------
__global__ void detect_dtype(const ushort_t* __restrict__ x, int* __restrict__ flag) {
    int cnt = 0;
    #pragma unroll
    for (int i = 0; i < 8; i++) {
        const int e = (x[2 * (threadIdx.x * 8 + i)] >> 7) & 0xFF;
        const unsigned long long m = __ballot(e >= 100 && e <= 140);
        cnt += (int)__popcll(m);
    }
    if (threadIdx.x == 0) *flag = (cnt >= 400) ? 1 : 0;
}

// -------- 4x weight transpose+convert: in[k][n] -> out bf16 [n][k] ---------------
__global__ __launch_bounds__(256) void convert_wt4(const void* w0, const void* w1,
                                                   const void* w2, const void* w3,
                                                   ushort_t* o0, ushort_t* o1,
                                                   ushort_t* o2, ushort_t* o3,
                                                   const int* __restrict__ flag) {
    __shared__ ushort_t tile[32][33];
    const void* in = (blockIdx.z == 0) ? w0 : (blockIdx.z == 1) ? w1 : (blockIdx.z == 2) ? w2 : w3;
    ushort_t*  out = (blockIdx.z == 0) ? o0 : (blockIdx.z == 1) ? o1 : (blockIdx.z == 2) ? o2 : o3;
    const int am = *flag;
    const int bx = blockIdx.x * 32, by = blockIdx.y * 32;
    const int tx = threadIdx.x & 31, ty = threadIdx.x >> 5;
    #pragma unroll
    for (int r = ty; r < 32; r += 8) {
        const size_t idx = (size_t)(by + r) * CH + bx + tx;
        tile[r][tx] = am ? ((const ushort_t*)in)[idx] : f2b(((const float*)in)[idx]);
    }
    __syncthreads();
    #pragma unroll
    for (int r = ty; r < 32; r += 8)
        out[(size_t)(bx + r) * CH + by + tx] = tile[tx][r];
}

// -------- 4x bias convert --------------------------------------------------------
__global__ void convert_bias4(const void* b0, const void* b1, const void* b2, const void* b3,
                              ushort_t* __restrict__ out, const int* __restrict__ flag) {
    const int i = blockIdx.x * 256 + threadIdx.x;  // 0..4095
    const int m = i >> 10, idx = i & 1023;
    const void* in = (m == 0) ? b0 : (m == 1) ? b1 : (m == 2) ? b2 : b3;
    out[i] = (*flag) ? ((const ushort_t*)in)[idx] : f2b(((const float*)in)[idx]);
}

// -------- x convert: flat fp32/bf16 -> bf16, 8 elems/thread ----------------------
__global__ __launch_bounds__(256) void convert_x(const void* __restrict__ in,
                                                 ushort_t* __restrict__ out,
                                                 const int* __restrict__ flag) {
    const int i = (blockIdx.x * 256 + threadIdx.x) * 8;
    if (*flag) {
        *(float4*)&out[i] = *(const float4*)&((const ushort_t*)in)[i];
    } else {
        const float* p = (const float*)in + i;
        float4 f0 = *(const float4*)p;
        float4 f1 = *(const float4*)(p + 4);
        ushort_t t[8] = {f2b(f0.x), f2b(f0.y), f2b(f0.z), f2b(f0.w),
                         f2b(f1.x), f2b(f1.y), f2b(f1.z), f2b(f1.w)};
        *(float4*)&out[i] = *(const float4*)t;
    }
}

// ---------------- fused QKV GEMM: [8192,1024] @ [3072,1024]^T + bias -------------
__global__ __launch_bounds__(256) void gemm_qkv(const ushort_t* __restrict__ A,
                                                const ushort_t* __restrict__ Bt,
                                                const ushort_t* __restrict__ bias,
                                                ushort_t* __restrict__ Qb,
                                                ushort_t* __restrict__ Kb,
                                                ushort_t* __restrict__ Vt,
                                                float qscale) {
    __shared__ __align__(16) ushort_t As[128 * 32];
    __shared__ __align__(16) ushort_t Bs[128 * 32];
    const int K = CH;
    const int tid = threadIdx.x;
    const int lane = tid & 63, wave = tid >> 6;
    const int lane15 = lane & 15, quad = lane >> 4;
    const int wr = (wave >> 1) * 64, wc = (wave & 1) * 64;
    const int row0 = blockIdx.x * 128, col0 = blockIdx.y * 128;
    const int seg = blockIdx.y >> 3;  // 0=Q 1=K 2=V

    floatx4 acc[4][4];
    #pragma unroll
    for (int i = 0; i < 4; i++)
        #pragma unroll
        for (int j = 0; j < 4; j++) acc[i][j] = {0.f, 0.f, 0.f, 0.f};

    for (int k0 = 0; k0 < K; k0 += 32) {
        #pragma unroll
        for (int l = wave; l < 8; l += 4) {
            GLD16(A  + (size_t)(row0 + l * 16 + (lane >> 2)) * K + k0 + (lane & 3) * 8, &As[l * 512]);
            GLD16(Bt + (size_t)(col0 + l * 16 + (lane >> 2)) * K + k0 + (lane & 3) * 8, &Bs[l * 512]);
        }
        __syncthreads();
        short8 af[4], bfr[4];
        #pragma unroll
        for (int i = 0; i < 4; i++)
            af[i] = *(const short8*)&As[(wr + i * 16 + lane15) * 32 + quad * 8];
        #pragma unroll
        for (int j = 0; j < 4; j++)
            bfr[j] = *(const short8*)&Bs[(wc + j * 16 + lane15) * 32 + quad * 8];
        #pragma unroll
        for (int i = 0; i < 4; i++)
            #pragma unroll
            for (int j = 0; j < 4; j++)
                acc[i][j] = __builtin_amdgcn_mfma_f32_16x16x32_bf16(af[i], bfr[j], acc[i][j], 0, 0, 0);
        __syncthreads();
    }

    #pragma unroll
    for (int j = 0; j < 4; j++) {
        const int col = col0 + wc + j * 16 + lane15;
        const float bv = b2f(bias[col]);
        #pragma unroll
        for (int i = 0; i < 4; i++) {
            const int rowb = row0 + wr + i * 16 + quad * 4;
            if (seg == 0) {
                #pragma unroll
                for (int r = 0; r < 4; r++)
                    Qb[(size_t)(rowb + r) * CH + col] = f2b((acc[i][j][r] + bv) * qscale);
            } else if (seg == 1) {
                const int c = col - 1024;
                #pragma unroll
                for (int r = 0; r < 4; r++)
                    Kb[(size_t)(rowb + r) * CH + c] = f2b(acc[i][j][r] + bv);
            } else {
                const int c = col - 2048;
                ushort_t pk[4];
                #pragma unroll
                for (int r = 0; r < 4; r++) pk[r] = f2b(acc[i][j][r] + bv);
                const int bb = rowb >> 11, t = rowb & 2047;
                *(uint2*)&Vt[((size_t)bb * 1024 + c) * 2048 + t] = *(const uint2*)pk;
            }
        }
    }
}

// ---------------- output GEMM: Out[M,N] = A @ Bt^T + bias (fp32 or bf16 out) -----
__global__ __launch_bounds__(256) void gemm_bt(const ushort_t* __restrict__ A,
                                               const ushort_t* __restrict__ Bt,
                                               const ushort_t* __restrict__ bias,
                                               void* __restrict__ Out,
                                               int M, int N, int K,
                                               const int* __restrict__ oflag) {
    __shared__ __align__(16) ushort_t As[128 * 32];
    __shared__ __align__(16) ushort_t Bs[128 * 32];
    const int om = *oflag;
    const int tid = threadIdx.x;
    const int lane = tid & 63, wave = tid >> 6;
    const int lane15 = lane & 15, quad = lane >> 4;
    const int wr = (wave >> 1) * 64, wc = (wave & 1) * 64;
    const int row0 = blockIdx.x * 128, col0 = blockIdx.y * 128;

    floatx4 acc[4][4];
    #pragma unroll
    for (int i = 0; i < 4; i++)
        #pragma unroll
        for (int j = 0; j < 4; j++) acc[i][j] = {0.f, 0.f, 0.f, 0.f};

    for (int k0 = 0; k0 < K; k0 += 32) {
        #pragma unroll
        for (int l = wave; l < 8; l += 4) {
            GLD16(A  + (size_t)(row0 + l * 16 + (lane >> 2)) * K + k0 + (lane & 3) * 8, &As[l * 512]);
            GLD16(Bt + (size_t)(col0 + l * 16 + (lane >> 2)) * K + k0 + (lane & 3) * 8, &Bs[l * 512]);
        }
        __syncthreads();
        short8 af[4], bfr[4];
        #pragma unroll
        for (int i = 0; i < 4; i++)
            af[i] = *(const short8*)&As[(wr + i * 16 + lane15) * 32 + quad * 8];
        #pragma unroll
        for (int j = 0; j < 4; j++)
            bfr[j] = *(const short8*)&Bs[(wc + j * 16 + lane15) * 32 + quad * 8];
        #pragma unroll
        for (int i = 0; i < 4; i++)
            #pragma unroll
            for (int j = 0; j < 4; j++)
                acc[i][j] = __builtin_amdgcn_mfma_f32_16x16x32_bf16(af[i], bfr[j], acc[i][j], 0, 0, 0);
        __syncthreads();
    }

    #pragma unroll
    for (int j = 0; j < 4; j++) {
        const int col = col0 + wc + j * 16 + lane15;
        const float bv = b2f(bias[col]);
        #pragma unroll
        for (int i = 0; i < 4; i++) {
            const int rowb = row0 + wr + i * 16 + quad * 4;
            #pragma unroll
            for (int r = 0; r < 4; r++) {
                const float val = acc[i][j][r] + bv;
                const size_t idx = (size_t)(rowb + r) * N + col;
                if (om) ((ushort_t*)Out)[idx] = f2b(val);
                else    ((float*)Out)[idx] = val;
            }
        }
    }
}

// ---------------- flash attention (S^T form: no P LDS round-trip) ----------------
// S^T = K.Q^T (K-tile as A-operand, Q regs as B-operand: A/B frag layouts are
// mutually transposed). S^T C-layout: kv = i*16+quad*4+r, q = lane15. exp2 in
// regs, pack to bf16 pairs, build PV B-frags (B[k=kv][n=q]) via quad-gather
// shuffles: target (quad,l15) j -> src lane (2(quad&1)+(j>=4))*16+l15, pair
// i = 2kk+(quad>>1), r = j&3. O^T = V^T.P^T (V^T-tile as A). Rowsum l via
// ones-as-A MFMA. LDS = 32KB (K/V dbuf only) -> 5 blocks/CU target.
__global__ __launch_bounds__(256, 4) void attn_fwd(ushort_t* __restrict__ QY,
                                                   const ushort_t* __restrict__ K,
                                                   const ushort_t* __restrict__ Vt) {
    __shared__ __align__(16) ushort_t Ks[2][64 * 64];    // [buf][kv][d], swizzled
    __shared__ __align__(16) ushort_t Vs[2][64 * 64];    // [buf][d][kv], swizzled
    const int tid = threadIdx.x;
    const int lane = tid & 63, wave = tid >> 6;
    const int lane15 = lane & 15, quad = lane >> 4;
    const int sw = lane15 & 7;                            // read-side swizzle key
    const int bid = blockIdx.x;
    const int hb = bid & 63, qslot = bid >> 6;
    const int qb = 15 - qslot;
    const int h = hb & 15, b = hb >> 4;
    const int q0 = qb * 128;
    const size_t baseR = (size_t)b * SEQ * CH + h * HSZ;      // +t*CH+d (Q,K,Y)
    const size_t baseV = ((size_t)b * 1024 + h * HSZ) * SEQ;  // +d*SEQ+t (Vt)
    const int rg = lane >> 3, cg = (lane & 7) ^ rg;           // staging swizzle
    const int srcA = (quad & 1) * 32 + lane15;                // P^T gather src lanes
    const int srcB = srcA + 16;
    const int hi = quad >> 1;

    short8 qf[2][2];
    #pragma unroll
    for (int mm = 0; mm < 2; mm++) {
        const ushort_t* qp = QY + baseR + (size_t)(q0 + wave * 32 + mm * 16 + lane15) * CH + quad * 8;
        qf[mm][0] = *(const short8*)qp;
        qf[mm][1] = *(const short8*)(qp + 32);
    }
    const short8 kOnes = (short8)(short)0x3F80;  // bf16 1.0 x8

    floatx4 o[2][5];  // [mm][0..3] = O^T d-chunks, [4] = l (rowsum)
    #pragma unroll
    for (int mm = 0; mm < 2; mm++)
        #pragma unroll
        for (int j = 0; j < 5; j++) o[mm][j] = {0.f, 0.f, 0.f, 0.f};

    const int nkt = 2 * qb + 2;
    #pragma unroll
    for (int l = wave; l < 8; l += 4) {
        GLD16(K  + baseR + (size_t)(l * 8 + rg) * CH + cg * 8, &Ks[0][l * 512]);
        GLD16(Vt + baseV + (size_t)(l * 8 + rg) * SEQ + cg * 8, &Vs[0][l * 512]);
    }

    for (int kt = 0; kt < nkt; kt++) {
        __syncthreads();  // staging of kt landed; all waves done with buf kt^1
        const int cur = kt & 1;
        if (kt + 1 < nkt) {
            const int kv1 = (kt + 1) * 64, nb = cur ^ 1;
            #pragma unroll
            for (int l = wave; l < 8; l += 4) {
                GLD16(K  + baseR + (size_t)(kv1 + l * 8 + rg) * CH + cg * 8, &Ks[nb][l * 512]);
                GLD16(Vt + baseV + (size_t)(l * 8 + rg) * SEQ + kv1 + cg * 8, &Vs[nb][l * 512]);
            }
        }
        const int kv0 = kt * 64;
        const int masked = (kt >= 2 * qb);
        #pragma unroll
        for (int mm = 0; mm < 2; mm++) {
            const int qg = q0 + wave * 32 + mm * 16 + lane15;  // this lane's q col
            // S^T = K.Q^T over 4 kv 16-chunks
            unsigned int pk[4][2];
            #pragma unroll
            for (int i = 0; i < 4; i++) {
                short8 a0 = *(const short8*)&Ks[cur][(i * 16 + lane15) * 64 + ((quad ^ sw) * 8)];
                short8 a1 = *(const short8*)&Ks[cur][(i * 16 + lane15) * 64 + (((quad + 4) ^ sw) * 8)];
                floatx4 z = {0.f, 0.f, 0.f, 0.f};
                z = __builtin_amdgcn_mfma_f32_16x16x32_bf16(a0, qf[mm][0], z, 0, 0, 0);
                z = __builtin_amdgcn_mfma_f32_16x16x32_bf16(a1, qf[mm][1], z, 0, 0, 0);
                float p[4];
                #pragma unroll
                for (int r = 0; r < 4; r++) {
                    float v = z[r];
                    if (masked) {
                        const int kvg = kv0 + i * 16 + quad * 4 + r;
                        v = (kvg <= qg) ? v : -1e30f;
                    }
                    p[r] = exp2f(v);
                }
                pk[i][0] = (unsigned int)f2b(p[0]) | ((unsigned int)f2b(p[1]) << 16);
                pk[i][1] = (unsigned int)f2b(p[2]) | ((unsigned int)f2b(p[3]) << 16);
            }
            // build P^T B-frags via quad-gather and run PV + rowsum
            #pragma unroll
            for (int kk = 0; kk < 2; kk++) {
                union { unsigned int u[4]; short8 s8; } pb;
                {
                    const unsigned int a0 = __shfl((int)pk[2 * kk + 0][0], srcA, 64);
                    const unsigned int a1 = __shfl((int)pk[2 * kk + 1][0], srcA, 64);
                    pb.u[0] = hi ? a1 : a0;
                }
                {
                    const unsigned int a0 = __shfl((int)pk[2 * kk + 0][1], srcA, 64);
                    const unsigned int a1 = __shfl((int)pk[2 * kk + 1][1], srcA, 64);
                    pb.u[1] = hi ? a1 : a0;
                }
                {
                    const unsigned int b0 = __shfl((int)pk[2 * kk + 0][0], srcB, 64);
                    const unsigned int b1 = __shfl((int)pk[2 * kk + 1][0], srcB, 64);
                    pb.u[2] = hi ? b1 : b0;
                }
                {
                    const unsigned int b0 = __shfl((int)pk[2 * kk + 0][1], srcB, 64);
                    const unsigned int b1 = __shfl((int)pk[2 * kk + 1][1], srcB, 64);
                    pb.u[3] = hi ? b1 : b0;
                }
                #pragma unroll
                for (int jn = 0; jn < 4; jn++) {
                    short8 vf = *(const short8*)&Vs[cur][(jn * 16 + lane15) * 64 + (((kk * 4 + quad) ^ sw) * 8)];
                    o[mm][jn] = __builtin_amdgcn_mfma_f32_16x16x32_bf16(vf, pb.s8, o[mm][jn], 0, 0, 0);
                }
                o[mm][4] = __builtin_amdgcn_mfma_f32_16x16x32_bf16(kOnes, pb.s8, o[mm][4], 0, 0, 0);
            }
        }
    }

    // epilogue: Y = O / l.  O^T C-layout: q = lane15, d = jn*16 + quad*4 + r
    // -> 4 consecutive d per (jn): packed 8B store.
    #pragma unroll
    for (int mm = 0; mm < 2; mm++) {
        const int qg = q0 + wave * 32 + mm * 16 + lane15;
        const float rinv = 1.0f / fmaxf(o[mm][4][0], 1e-30f);
        #pragma unroll
        for (int jn = 0; jn < 4; jn++) {
            ushort_t pkk[4];
            #pragma unroll
            for (int r = 0; r < 4; r++) pkk[r] = f2b(o[mm][jn][r] * rinv);
            *(uint2*)&QY[baseR + (size_t)qg * CH + jn * 16 + quad * 4] = *(const uint2*)pkk;
        }
    }
}

extern "C" void kernel_launch(void* const* d_in, const int* in_sizes, int n_in,
                              void* d_out, int out_size, void* d_ws, size_t ws_size,
                              hipStream_t stream) {
    const void* x  = d_in[0];
    const void* Wk = d_in[1];
    const void* bk = d_in[2];
    const void* Wq = d_in[3];
    const void* bq = d_in[4];
    const void* Wv = d_in[5];
    const void* bv = d_in[6];
    const void* Wo = d_in[7];
    const void* bo = d_in[8];

    ushort_t* ws    = (ushort_t*)d_ws;
    int*      flag  = (int*)d_ws;
    ushort_t* biasC = ws + 2048;                    // 4x1024: q,k,v,o (contiguous)
    ushort_t* WqkvT = ws + 32768;                   // 3x1M contiguous: q,k,v
    ushort_t* WoT   = WqkvT + 3u * (1u << 20);
    ushort_t* xb    = ws + 4227072;                 // 8M elems bf16
    ushort_t* Qb    = ws + 12615680;                // 8M elems (becomes Y)
    ushort_t* Kb    = (ushort_t*)d_out;             // d_out scratch until final GEMM
    ushort_t* VtB   = Kb + (size_t)MROWS * CH;

    detect_dtype<<<1, 64, 0, stream>>>((const ushort_t*)x, flag);

    dim3 tgrid(32, 32, 4);
    convert_wt4<<<tgrid, 256, 0, stream>>>(Wq, Wk, Wv, Wo,
                                           WqkvT, WqkvT + (1u << 20), WqkvT + 2u * (1u << 20), WoT, flag);
    convert_bias4<<<16, 256, 0, stream>>>(bq, bk, bv, bo, biasC, flag);
    convert_x<<<MROWS * CH / (256 * 8), 256, 0, stream>>>(x, xb, flag);

    // scale = (1/sqrt(64)) * log2(e), folded into Q so attention uses exp2
    dim3 qgrid(MROWS / 128, 3 * CH / 128);
    gemm_qkv<<<qgrid, 256, 0, stream>>>(xb, WqkvT, biasC, Qb, Kb, VtB, 0.1803368801f);

    attn_fwd<<<dim3(1024), 256, 0, stream>>>(Qb, Kb, VtB);

    dim3 ogrid(MROWS / 128, CH / 128);
    gemm_bt<<<ogrid, 256, 0, stream>>>(Qb, WoT, biasC + 3072, d_out, MROWS, CH, CH, flag);
}

// Round 8
// 296.096 us; speedup vs baseline: 1.4570x; 1.4570x over previous
//
#include <hip/hip_runtime.h>
#include <hip/hip_bf16.h>

typedef unsigned short ushort_t;
typedef __attribute__((ext_vector_type(8))) short short8;   // 8 x bf16 (4 VGPRs)
typedef __attribute__((ext_vector_type(4))) float floatx4;  // MFMA acc

#define BATCH 4
#define SEQ   2048
#define CH    1024
#define NHEAD 16
#define HSZ   64
#define MROWS (BATCH * SEQ)  // 8192

// async global->LDS, 16B per lane; LDS dest = wave-uniform base + lane*16
#define GLD16(gptr, lptr) \
    __builtin_amdgcn_global_load_lds((const __attribute__((address_space(1))) unsigned int*)(gptr), \
                                     (__attribute__((address_space(3))) unsigned int*)(lptr), 16, 0, 0)

__device__ inline ushort_t f2b(float f) {
    __hip_bfloat16 h = __float2bfloat16(f);
    return *(ushort_t*)&h;
}
__device__ inline float b2f(ushort_t u) {
    return __bfloat162float(*(__hip_bfloat16*)&u);
}

// -------- dtype detect (parallel): *flag = 1 if x is bf16, 0 if f32 --------------
__global__ void detect_dtype(const ushort_t* __restrict__ x, int* __restrict__ flag) {
    int cnt = 0;
    #pragma unroll
    for (int i = 0; i < 8; i++) {
        const int e = (x[2 * (threadIdx.x * 8 + i)] >> 7) & 0xFF;
        const unsigned long long m = __ballot(e >= 100 && e <= 140);
        cnt += (int)__popcll(m);
    }
    if (threadIdx.x == 0) *flag = (cnt >= 400) ? 1 : 0;
}

// -------- 4x weight transpose+convert: in[k][n] -> out bf16 [n][k] ---------------
__global__ __launch_bounds__(256) void convert_wt4(const void* w0, const void* w1,
                                                   const void* w2, const void* w3,
                                                   ushort_t* o0, ushort_t* o1,
                                                   ushort_t* o2, ushort_t* o3,
                                                   const int* __restrict__ flag) {
    __shared__ ushort_t tile[32][33];
    const void* in = (blockIdx.z == 0) ? w0 : (blockIdx.z == 1) ? w1 : (blockIdx.z == 2) ? w2 : w3;
    ushort_t*  out = (blockIdx.z == 0) ? o0 : (blockIdx.z == 1) ? o1 : (blockIdx.z == 2) ? o2 : o3;
    const int am = *flag;
    const int bx = blockIdx.x * 32, by = blockIdx.y * 32;
    const int tx = threadIdx.x & 31, ty = threadIdx.x >> 5;
    #pragma unroll
    for (int r = ty; r < 32; r += 8) {
        const size_t idx = (size_t)(by + r) * CH + bx + tx;
        tile[r][tx] = am ? ((const ushort_t*)in)[idx] : f2b(((const float*)in)[idx]);
    }
    __syncthreads();
    #pragma unroll
    for (int r = ty; r < 32; r += 8)
        out[(size_t)(bx + r) * CH + by + tx] = tile[tx][r];
}

// -------- 4x bias convert --------------------------------------------------------
__global__ void convert_bias4(const void* b0, const void* b1, const void* b2, const void* b3,
                              ushort_t* __restrict__ out, const int* __restrict__ flag) {
    const int i = blockIdx.x * 256 + threadIdx.x;  // 0..4095
    const int m = i >> 10, idx = i & 1023;
    const void* in = (m == 0) ? b0 : (m == 1) ? b1 : (m == 2) ? b2 : b3;
    out[i] = (*flag) ? ((const ushort_t*)in)[idx] : f2b(((const float*)in)[idx]);
}

// -------- x convert: flat fp32/bf16 -> bf16, 8 elems/thread ----------------------
__global__ __launch_bounds__(256) void convert_x(const void* __restrict__ in,
                                                 ushort_t* __restrict__ out,
                                                 const int* __restrict__ flag) {
    const int i = (blockIdx.x * 256 + threadIdx.x) * 8;
    if (*flag) {
        *(float4*)&out[i] = *(const float4*)&((const ushort_t*)in)[i];
    } else {
        const float* p = (const float*)in + i;
        float4 f0 = *(const float4*)p;
        float4 f1 = *(const float4*)(p + 4);
        ushort_t t[8] = {f2b(f0.x), f2b(f0.y), f2b(f0.z), f2b(f0.w),
                         f2b(f1.x), f2b(f1.y), f2b(f1.z), f2b(f1.w)};
        *(float4*)&out[i] = *(const float4*)t;
    }
}

// ---------------- fused QKV GEMM: [8192,1024] @ [3072,1024]^T + bias -------------
__global__ __launch_bounds__(256) void gemm_qkv(const ushort_t* __restrict__ A,
                                                const ushort_t* __restrict__ Bt,
                                                const ushort_t* __restrict__ bias,
                                                ushort_t* __restrict__ Qb,
                                                ushort_t* __restrict__ Kb,
                                                ushort_t* __restrict__ Vt,
                                                float qscale) {
    __shared__ __align__(16) ushort_t As[128 * 32];
    __shared__ __align__(16) ushort_t Bs[128 * 32];
    const int K = CH;
    const int tid = threadIdx.x;
    const int lane = tid & 63, wave = tid >> 6;
    const int lane15 = lane & 15, quad = lane >> 4;
    const int wr = (wave >> 1) * 64, wc = (wave & 1) * 64;
    const int row0 = blockIdx.x * 128, col0 = blockIdx.y * 128;
    const int seg = blockIdx.y >> 3;  // 0=Q 1=K 2=V

    floatx4 acc[4][4];
    #pragma unroll
    for (int i = 0; i < 4; i++)
        #pragma unroll
        for (int j = 0; j < 4; j++) acc[i][j] = {0.f, 0.f, 0.f, 0.f};

    for (int k0 = 0; k0 < K; k0 += 32) {
        #pragma unroll
        for (int l = wave; l < 8; l += 4) {
            GLD16(A  + (size_t)(row0 + l * 16 + (lane >> 2)) * K + k0 + (lane & 3) * 8, &As[l * 512]);
            GLD16(Bt + (size_t)(col0 + l * 16 + (lane >> 2)) * K + k0 + (lane & 3) * 8, &Bs[l * 512]);
        }
        __syncthreads();
        short8 af[4], bfr[4];
        #pragma unroll
        for (int i = 0; i < 4; i++)
            af[i] = *(const short8*)&As[(wr + i * 16 + lane15) * 32 + quad * 8];
        #pragma unroll
        for (int j = 0; j < 4; j++)
            bfr[j] = *(const short8*)&Bs[(wc + j * 16 + lane15) * 32 + quad * 8];
        #pragma unroll
        for (int i = 0; i < 4; i++)
            #pragma unroll
            for (int j = 0; j < 4; j++)
                acc[i][j] = __builtin_amdgcn_mfma_f32_16x16x32_bf16(af[i], bfr[j], acc[i][j], 0, 0, 0);
        __syncthreads();
    }

    #pragma unroll
    for (int j = 0; j < 4; j++) {
        const int col = col0 + wc + j * 16 + lane15;
        const float bv = b2f(bias[col]);
        #pragma unroll
        for (int i = 0; i < 4; i++) {
            const int rowb = row0 + wr + i * 16 + quad * 4;
            if (seg == 0) {
                #pragma unroll
                for (int r = 0; r < 4; r++)
                    Qb[(size_t)(rowb + r) * CH + col] = f2b((acc[i][j][r] + bv) * qscale);
            } else if (seg == 1) {
                const int c = col - 1024;
                #pragma unroll
                for (int r = 0; r < 4; r++)
                    Kb[(size_t)(rowb + r) * CH + c] = f2b(acc[i][j][r] + bv);
            } else {
                const int c = col - 2048;
                ushort_t pk[4];
                #pragma unroll
                for (int r = 0; r < 4; r++) pk[r] = f2b(acc[i][j][r] + bv);
                const int bb = rowb >> 11, t = rowb & 2047;
                *(uint2*)&Vt[((size_t)bb * 1024 + c) * 2048 + t] = *(const uint2*)pk;
            }
        }
    }
}

// ---------------- output GEMM: Out[M,N] = A @ Bt^T + bias (fp32 or bf16 out) -----
__global__ __launch_bounds__(256) void gemm_bt(const ushort_t* __restrict__ A,
                                               const ushort_t* __restrict__ Bt,
                                               const ushort_t* __restrict__ bias,
                                               void* __restrict__ Out,
                                               int M, int N, int K,
                                               const int* __restrict__ oflag) {
    __shared__ __align__(16) ushort_t As[128 * 32];
    __shared__ __align__(16) ushort_t Bs[128 * 32];
    const int om = *oflag;
    const int tid = threadIdx.x;
    const int lane = tid & 63, wave = tid >> 6;
    const int lane15 = lane & 15, quad = lane >> 4;
    const int wr = (wave >> 1) * 64, wc = (wave & 1) * 64;
    const int row0 = blockIdx.x * 128, col0 = blockIdx.y * 128;

    floatx4 acc[4][4];
    #pragma unroll
    for (int i = 0; i < 4; i++)
        #pragma unroll
        for (int j = 0; j < 4; j++) acc[i][j] = {0.f, 0.f, 0.f, 0.f};

    for (int k0 = 0; k0 < K; k0 += 32) {
        #pragma unroll
        for (int l = wave; l < 8; l += 4) {
            GLD16(A  + (size_t)(row0 + l * 16 + (lane >> 2)) * K + k0 + (lane & 3) * 8, &As[l * 512]);
            GLD16(Bt + (size_t)(col0 + l * 16 + (lane >> 2)) * K + k0 + (lane & 3) * 8, &Bs[l * 512]);
        }
        __syncthreads();
        short8 af[4], bfr[4];
        #pragma unroll
        for (int i = 0; i < 4; i++)
            af[i] = *(const short8*)&As[(wr + i * 16 + lane15) * 32 + quad * 8];
        #pragma unroll
        for (int j = 0; j < 4; j++)
            bfr[j] = *(const short8*)&Bs[(wc + j * 16 + lane15) * 32 + quad * 8];
        #pragma unroll
        for (int i = 0; i < 4; i++)
            #pragma unroll
            for (int j = 0; j < 4; j++)
                acc[i][j] = __builtin_amdgcn_mfma_f32_16x16x32_bf16(af[i], bfr[j], acc[i][j], 0, 0, 0);
        __syncthreads();
    }

    #pragma unroll
    for (int j = 0; j < 4; j++) {
        const int col = col0 + wc + j * 16 + lane15;
        const float bv = b2f(bias[col]);
        #pragma unroll
        for (int i = 0; i < 4; i++) {
            const int rowb = row0 + wr + i * 16 + quad * 4;
            #pragma unroll
            for (int r = 0; r < 4; r++) {
                const float val = acc[i][j][r] + bv;
                const size_t idx = (size_t)(rowb + r) * N + col;
                if (om) ((ushort_t*)Out)[idx] = f2b(val);
                else    ((float*)Out)[idx] = val;
            }
        }
    }
}

// ---------------- flash attention (S^T form: no P LDS round-trip) ----------------
// S^T = K.Q^T (K-tile as A-operand, Q regs as B-operand). exp2 in regs, pack to
// bf16 pairs, build PV B-frags via quad-gather shuffles. O^T = V^T.P^T. Rowsum l
// via ones-as-A MFMA. LDS 32KB (K/V dbuf only).
// NO second launch_bounds arg: round-7's (256,4) clamped VGPR to 64 -> ~500 MB
// of scratch spill traffic (WRITE_SIZE 295 MB). Let the allocator take ~100.
__global__ __launch_bounds__(256) void attn_fwd(ushort_t* __restrict__ QY,
                                                const ushort_t* __restrict__ K,
                                                const ushort_t* __restrict__ Vt) {
    __shared__ __align__(16) ushort_t Ks[2][64 * 64];    // [buf][kv][d], swizzled
    __shared__ __align__(16) ushort_t Vs[2][64 * 64];    // [buf][d][kv], swizzled
    const int tid = threadIdx.x;
    const int lane = tid & 63, wave = tid >> 6;
    const int lane15 = lane & 15, quad = lane >> 4;
    const int sw = lane15 & 7;                            // read-side swizzle key
    const int bid = blockIdx.x;
    const int hb = bid & 63, qslot = bid >> 6;
    const int qb = 15 - qslot;
    const int h = hb & 15, b = hb >> 4;
    const int q0 = qb * 128;
    const size_t baseR = (size_t)b * SEQ * CH + h * HSZ;      // +t*CH+d (Q,K,Y)
    const size_t baseV = ((size_t)b * 1024 + h * HSZ) * SEQ;  // +d*SEQ+t (Vt)
    const int rg = lane >> 3, cg = (lane & 7) ^ rg;           // staging swizzle
    const int srcA = (quad & 1) * 32 + lane15;                // P^T gather src lanes
    const int srcB = srcA + 16;
    const int hi = quad >> 1;

    short8 qf[2][2];
    #pragma unroll
    for (int mm = 0; mm < 2; mm++) {
        const ushort_t* qp = QY + baseR + (size_t)(q0 + wave * 32 + mm * 16 + lane15) * CH + quad * 8;
        qf[mm][0] = *(const short8*)qp;
        qf[mm][1] = *(const short8*)(qp + 32);
    }
    const short8 kOnes = (short8)(short)0x3F80;  // bf16 1.0 x8

    floatx4 o[2][5];  // [mm][0..3] = O^T d-chunks, [4] = l (rowsum)
    #pragma unroll
    for (int mm = 0; mm < 2; mm++)
        #pragma unroll
        for (int j = 0; j < 5; j++) o[mm][j] = {0.f, 0.f, 0.f, 0.f};

    const int nkt = 2 * qb + 2;
    #pragma unroll
    for (int l = wave; l < 8; l += 4) {
        GLD16(K  + baseR + (size_t)(l * 8 + rg) * CH + cg * 8, &Ks[0][l * 512]);
        GLD16(Vt + baseV + (size_t)(l * 8 + rg) * SEQ + cg * 8, &Vs[0][l * 512]);
    }

    for (int kt = 0; kt < nkt; kt++) {
        __syncthreads();  // staging of kt landed; all waves done with buf kt^1
        const int cur = kt & 1;
        if (kt + 1 < nkt) {
            const int kv1 = (kt + 1) * 64, nb = cur ^ 1;
            #pragma unroll
            for (int l = wave; l < 8; l += 4) {
                GLD16(K  + baseR + (size_t)(kv1 + l * 8 + rg) * CH + cg * 8, &Ks[nb][l * 512]);
                GLD16(Vt + baseV + (size_t)(l * 8 + rg) * SEQ + kv1 + cg * 8, &Vs[nb][l * 512]);
            }
        }
        const int kv0 = kt * 64;
        const int masked = (kt >= 2 * qb);
        #pragma unroll
        for (int mm = 0; mm < 2; mm++) {
            const int qg = q0 + wave * 32 + mm * 16 + lane15;  // this lane's q col
            // S^T = K.Q^T over 4 kv 16-chunks
            unsigned int pk[4][2];
            #pragma unroll
            for (int i = 0; i < 4; i++) {
                short8 a0 = *(const short8*)&Ks[cur][(i * 16 + lane15) * 64 + ((quad ^ sw) * 8)];
                short8 a1 = *(const short8*)&Ks[cur][(i * 16 + lane15) * 64 + (((quad + 4) ^ sw) * 8)];
                floatx4 z = {0.f, 0.f, 0.f, 0.f};
                z = __builtin_amdgcn_mfma_f32_16x16x32_bf16(a0, qf[mm][0], z, 0, 0, 0);
                z = __builtin_amdgcn_mfma_f32_16x16x32_bf16(a1, qf[mm][1], z, 0, 0, 0);
                float p[4];
                #pragma unroll
                for (int r = 0; r < 4; r++) {
                    float v = z[r];
                    if (masked) {
                        const int kvg = kv0 + i * 16 + quad * 4 + r;
                        v = (kvg <= qg) ? v : -1e30f;
                    }
                    p[r] = exp2f(v);
                }
                pk[i][0] = (unsigned int)f2b(p[0]) | ((unsigned int)f2b(p[1]) << 16);
                pk[i][1] = (unsigned int)f2b(p[2]) | ((unsigned int)f2b(p[3]) << 16);
            }
            // build P^T B-frags via quad-gather and run PV + rowsum
            #pragma unroll
            for (int kk = 0; kk < 2; kk++) {
                union { unsigned int u[4]; short8 s8; } pb;
                {
                    const unsigned int a0 = __shfl((int)pk[2 * kk + 0][0], srcA, 64);
                    const unsigned int a1 = __shfl((int)pk[2 * kk + 1][0], srcA, 64);
                    pb.u[0] = hi ? a1 : a0;
                }
                {
                    const unsigned int a0 = __shfl((int)pk[2 * kk + 0][1], srcA, 64);
                    const unsigned int a1 = __shfl((int)pk[2 * kk + 1][1], srcA, 64);
                    pb.u[1] = hi ? a1 : a0;
                }
                {
                    const unsigned int b0 = __shfl((int)pk[2 * kk + 0][0], srcB, 64);
                    const unsigned int b1 = __shfl((int)pk[2 * kk + 1][0], srcB, 64);
                    pb.u[2] = hi ? b1 : b0;
                }
                {
                    const unsigned int b0 = __shfl((int)pk[2 * kk + 0][1], srcB, 64);
                    const unsigned int b1 = __shfl((int)pk[2 * kk + 1][1], srcB, 64);
                    pb.u[3] = hi ? b1 : b0;
                }
                #pragma unroll
                for (int jn = 0; jn < 4; jn++) {
                    short8 vf = *(const short8*)&Vs[cur][(jn * 16 + lane15) * 64 + (((kk * 4 + quad) ^ sw) * 8)];
                    o[mm][jn] = __builtin_amdgcn_mfma_f32_16x16x32_bf16(vf, pb.s8, o[mm][jn], 0, 0, 0);
                }
                o[mm][4] = __builtin_amdgcn_mfma_f32_16x16x32_bf16(kOnes, pb.s8, o[mm][4], 0, 0, 0);
            }
        }
    }

    // epilogue: Y = O / l.  O^T C-layout: q = lane15, d = jn*16 + quad*4 + r
    // -> 4 consecutive d per (jn): packed 8B store.
    #pragma unroll
    for (int mm = 0; mm < 2; mm++) {
        const int qg = q0 + wave * 32 + mm * 16 + lane15;
        const float rinv = 1.0f / fmaxf(o[mm][4][0], 1e-30f);
        #pragma unroll
        for (int jn = 0; jn < 4; jn++) {
            ushort_t pkk[4];
            #pragma unroll
            for (int r = 0; r < 4; r++) pkk[r] = f2b(o[mm][jn][r] * rinv);
            *(uint2*)&QY[baseR + (size_t)qg * CH + jn * 16 + quad * 4] = *(const uint2*)pkk;
        }
    }
}

extern "C" void kernel_launch(void* const* d_in, const int* in_sizes, int n_in,
                              void* d_out, int out_size, void* d_ws, size_t ws_size,
                              hipStream_t stream) {
    const void* x  = d_in[0];
    const void* Wk = d_in[1];
    const void* bk = d_in[2];
    const void* Wq = d_in[3];
    const void* bq = d_in[4];
    const void* Wv = d_in[5];
    const void* bv = d_in[6];
    const void* Wo = d_in[7];
    const void* bo = d_in[8];

    ushort_t* ws    = (ushort_t*)d_ws;
    int*      flag  = (int*)d_ws;
    ushort_t* biasC = ws + 2048;                    // 4x1024: q,k,v,o (contiguous)
    ushort_t* WqkvT = ws + 32768;                   // 3x1M contiguous: q,k,v
    ushort_t* WoT   = WqkvT + 3u * (1u << 20);
    ushort_t* xb    = ws + 4227072;                 // 8M elems bf16
    ushort_t* Qb    = ws + 12615680;                // 8M elems (becomes Y)
    ushort_t* Kb    = (ushort_t*)d_out;             // d_out scratch until final GEMM
    ushort_t* VtB   = Kb + (size_t)MROWS * CH;

    detect_dtype<<<1, 64, 0, stream>>>((const ushort_t*)x, flag);

    dim3 tgrid(32, 32, 4);
    convert_wt4<<<tgrid, 256, 0, stream>>>(Wq, Wk, Wv, Wo,
                                           WqkvT, WqkvT + (1u << 20), WqkvT + 2u * (1u << 20), WoT, flag);
    convert_bias4<<<16, 256, 0, stream>>>(bq, bk, bv, bo, biasC, flag);
    convert_x<<<MROWS * CH / (256 * 8), 256, 0, stream>>>(x, xb, flag);

    // scale = (1/sqrt(64)) * log2(e), folded into Q so attention uses exp2
    dim3 qgrid(MROWS / 128, 3 * CH / 128);
    gemm_qkv<<<qgrid, 256, 0, stream>>>(xb, WqkvT, biasC, Qb, Kb, VtB, 0.1803368801f);

    attn_fwd<<<dim3(1024), 256, 0, stream>>>(Qb, Kb, VtB);

    dim3 ogrid(MROWS / 128, CH / 128);
    gemm_bt<<<ogrid, 256, 0, stream>>>(Qb, WoT, biasC + 3072, d_out, MROWS, CH, CH, flag);
}

// Round 9
// 270.262 us; speedup vs baseline: 1.5962x; 1.0956x over previous
//
#include <hip/hip_runtime.h>
#include <hip/hip_bf16.h>

typedef unsigned short ushort_t;
typedef __attribute__((ext_vector_type(8))) short short8;   // 8 x bf16 (4 VGPRs)
typedef __attribute__((ext_vector_type(4))) float floatx4;  // MFMA acc

#define BATCH 4
#define SEQ   2048
#define CH    1024
#define NHEAD 16
#define HSZ   64
#define MROWS (BATCH * SEQ)  // 8192

// async global->LDS, 16B per lane; LDS dest = wave-uniform base + lane*16
#define GLD16(gptr, lptr) \
    __builtin_amdgcn_global_load_lds((const __attribute__((address_space(1))) unsigned int*)(gptr), \
                                     (__attribute__((address_space(3))) unsigned int*)(lptr), 16, 0, 0)

__device__ inline ushort_t f2b(float f) {
    __hip_bfloat16 h = __float2bfloat16(f);
    return *(ushort_t*)&h;
}
__device__ inline float b2f(ushort_t u) {
    return __bfloat162float(*(__hip_bfloat16*)&u);
}

// -------- dtype detect (parallel): *flag = 1 if x is bf16, 0 if f32 --------------
__global__ void detect_dtype(const ushort_t* __restrict__ x, int* __restrict__ flag) {
    int cnt = 0;
    #pragma unroll
    for (int i = 0; i < 8; i++) {
        const int e = (x[2 * (threadIdx.x * 8 + i)] >> 7) & 0xFF;
        const unsigned long long m = __ballot(e >= 100 && e <= 140);
        cnt += (int)__popcll(m);
    }
    if (threadIdx.x == 0) *flag = (cnt >= 400) ? 1 : 0;
}

// -------- 4x weight transpose+convert: in[k][n] -> out bf16 [n][k] ---------------
__global__ __launch_bounds__(256) void convert_wt4(const void* w0, const void* w1,
                                                   const void* w2, const void* w3,
                                                   ushort_t* o0, ushort_t* o1,
                                                   ushort_t* o2, ushort_t* o3,
                                                   const int* __restrict__ flag) {
    __shared__ ushort_t tile[32][33];
    const void* in = (blockIdx.z == 0) ? w0 : (blockIdx.z == 1) ? w1 : (blockIdx.z == 2) ? w2 : w3;
    ushort_t*  out = (blockIdx.z == 0) ? o0 : (blockIdx.z == 1) ? o1 : (blockIdx.z == 2) ? o2 : o3;
    const int am = *flag;
    const int bx = blockIdx.x * 32, by = blockIdx.y * 32;
    const int tx = threadIdx.x & 31, ty = threadIdx.x >> 5;
    #pragma unroll
    for (int r = ty; r < 32; r += 8) {
        const size_t idx = (size_t)(by + r) * CH + bx + tx;
        tile[r][tx] = am ? ((const ushort_t*)in)[idx] : f2b(((const float*)in)[idx]);
    }
    __syncthreads();
    #pragma unroll
    for (int r = ty; r < 32; r += 8)
        out[(size_t)(bx + r) * CH + by + tx] = tile[tx][r];
}

// -------- 4x bias convert --------------------------------------------------------
__global__ void convert_bias4(const void* b0, const void* b1, const void* b2, const void* b3,
                              ushort_t* __restrict__ out, const int* __restrict__ flag) {
    const int i = blockIdx.x * 256 + threadIdx.x;  // 0..4095
    const int m = i >> 10, idx = i & 1023;
    const void* in = (m == 0) ? b0 : (m == 1) ? b1 : (m == 2) ? b2 : b3;
    out[i] = (*flag) ? ((const ushort_t*)in)[idx] : f2b(((const float*)in)[idx]);
}

// -------- x convert: flat fp32/bf16 -> bf16, 8 elems/thread ----------------------
__global__ __launch_bounds__(256) void convert_x(const void* __restrict__ in,
                                                 ushort_t* __restrict__ out,
                                                 const int* __restrict__ flag) {
    const int i = (blockIdx.x * 256 + threadIdx.x) * 8;
    if (*flag) {
        *(float4*)&out[i] = *(const float4*)&((const ushort_t*)in)[i];
    } else {
        const float* p = (const float*)in + i;
        float4 f0 = *(const float4*)p;
        float4 f1 = *(const float4*)(p + 4);
        ushort_t t[8] = {f2b(f0.x), f2b(f0.y), f2b(f0.z), f2b(f0.w),
                         f2b(f1.x), f2b(f1.y), f2b(f1.z), f2b(f1.w)};
        *(float4*)&out[i] = *(const float4*)t;
    }
}

// ---------------- fused QKV GEMM: [8192,1024] @ [3072,1024]^T + bias -------------
__global__ __launch_bounds__(256) void gemm_qkv(const ushort_t* __restrict__ A,
                                                const ushort_t* __restrict__ Bt,
                                                const ushort_t* __restrict__ bias,
                                                ushort_t* __restrict__ Qb,
                                                ushort_t* __restrict__ Kb,
                                                ushort_t* __restrict__ Vt,
                                                float qscale) {
    __shared__ __align__(16) ushort_t As[128 * 32];
    __shared__ __align__(16) ushort_t Bs[128 * 32];
    const int K = CH;
    const int tid = threadIdx.x;
    const int lane = tid & 63, wave = tid >> 6;
    const int lane15 = lane & 15, quad = lane >> 4;
    const int wr = (wave >> 1) * 64, wc = (wave & 1) * 64;
    const int row0 = blockIdx.x * 128, col0 = blockIdx.y * 128;
    const int seg = blockIdx.y >> 3;  // 0=Q 1=K 2=V

    floatx4 acc[4][4];
    #pragma unroll
    for (int i = 0; i < 4; i++)
        #pragma unroll
        for (int j = 0; j < 4; j++) acc[i][j] = {0.f, 0.f, 0.f, 0.f};

    for (int k0 = 0; k0 < K; k0 += 32) {
        #pragma unroll
        for (int l = wave; l < 8; l += 4) {
            GLD16(A  + (size_t)(row0 + l * 16 + (lane >> 2)) * K + k0 + (lane & 3) * 8, &As[l * 512]);
            GLD16(Bt + (size_t)(col0 + l * 16 + (lane >> 2)) * K + k0 + (lane & 3) * 8, &Bs[l * 512]);
        }
        __syncthreads();
        short8 af[4], bfr[4];
        #pragma unroll
        for (int i = 0; i < 4; i++)
            af[i] = *(const short8*)&As[(wr + i * 16 + lane15) * 32 + quad * 8];
        #pragma unroll
        for (int j = 0; j < 4; j++)
            bfr[j] = *(const short8*)&Bs[(wc + j * 16 + lane15) * 32 + quad * 8];
        #pragma unroll
        for (int i = 0; i < 4; i++)
            #pragma unroll
            for (int j = 0; j < 4; j++)
                acc[i][j] = __builtin_amdgcn_mfma_f32_16x16x32_bf16(af[i], bfr[j], acc[i][j], 0, 0, 0);
        __syncthreads();
    }

    #pragma unroll
    for (int j = 0; j < 4; j++) {
        const int col = col0 + wc + j * 16 + lane15;
        const float bv = b2f(bias[col]);
        #pragma unroll
        for (int i = 0; i < 4; i++) {
            const int rowb = row0 + wr + i * 16 + quad * 4;
            if (seg == 0) {
                #pragma unroll
                for (int r = 0; r < 4; r++)
                    Qb[(size_t)(rowb + r) * CH + col] = f2b((acc[i][j][r] + bv) * qscale);
            } else if (seg == 1) {
                const int c = col - 1024;
                #pragma unroll
                for (int r = 0; r < 4; r++)
                    Kb[(size_t)(rowb + r) * CH + c] = f2b(acc[i][j][r] + bv);
            } else {
                const int c = col - 2048;
                ushort_t pk[4];
                #pragma unroll
                for (int r = 0; r < 4; r++) pk[r] = f2b(acc[i][j][r] + bv);
                const int bb = rowb >> 11, t = rowb & 2047;
                *(uint2*)&Vt[((size_t)bb * 1024 + c) * 2048 + t] = *(const uint2*)pk;
            }
        }
    }
}

// ---------------- output GEMM: Out[M,N] = A @ Bt^T + bias (fp32 or bf16 out) -----
__global__ __launch_bounds__(256) void gemm_bt(const ushort_t* __restrict__ A,
                                               const ushort_t* __restrict__ Bt,
                                               const ushort_t* __restrict__ bias,
                                               void* __restrict__ Out,
                                               int M, int N, int K,
                                               const int* __restrict__ oflag) {
    __shared__ __align__(16) ushort_t As[128 * 32];
    __shared__ __align__(16) ushort_t Bs[128 * 32];
    const int om = *oflag;
    const int tid = threadIdx.x;
    const int lane = tid & 63, wave = tid >> 6;
    const int lane15 = lane & 15, quad = lane >> 4;
    const int wr = (wave >> 1) * 64, wc = (wave & 1) * 64;
    const int row0 = blockIdx.x * 128, col0 = blockIdx.y * 128;

    floatx4 acc[4][4];
    #pragma unroll
    for (int i = 0; i < 4; i++)
        #pragma unroll
        for (int j = 0; j < 4; j++) acc[i][j] = {0.f, 0.f, 0.f, 0.f};

    for (int k0 = 0; k0 < K; k0 += 32) {
        #pragma unroll
        for (int l = wave; l < 8; l += 4) {
            GLD16(A  + (size_t)(row0 + l * 16 + (lane >> 2)) * K + k0 + (lane & 3) * 8, &As[l * 512]);
            GLD16(Bt + (size_t)(col0 + l * 16 + (lane >> 2)) * K + k0 + (lane & 3) * 8, &Bs[l * 512]);
        }
        __syncthreads();
        short8 af[4], bfr[4];
        #pragma unroll
        for (int i = 0; i < 4; i++)
            af[i] = *(const short8*)&As[(wr + i * 16 + lane15) * 32 + quad * 8];
        #pragma unroll
        for (int j = 0; j < 4; j++)
            bfr[j] = *(const short8*)&Bs[(wc + j * 16 + lane15) * 32 + quad * 8];
        #pragma unroll
        for (int i = 0; i < 4; i++)
            #pragma unroll
            for (int j = 0; j < 4; j++)
                acc[i][j] = __builtin_amdgcn_mfma_f32_16x16x32_bf16(af[i], bfr[j], acc[i][j], 0, 0, 0);
        __syncthreads();
    }

    #pragma unroll
    for (int j = 0; j < 4; j++) {
        const int col = col0 + wc + j * 16 + lane15;
        const float bv = b2f(bias[col]);
        #pragma unroll
        for (int i = 0; i < 4; i++) {
            const int rowb = row0 + wr + i * 16 + quad * 4;
            #pragma unroll
            for (int r = 0; r < 4; r++) {
                const float val = acc[i][j][r] + bv;
                const size_t idx = (size_t)(rowb + r) * N + col;
                if (om) ((ushort_t*)Out)[idx] = f2b(val);
                else    ((float*)Out)[idx] = val;
            }
        }
    }
}

// ---------------- flash attention (round-6 structure: measured best) -------------
// Ps LDS round-trip decouples the S-phase from PV (overlappable across waves) —
// measured 79 us vs 110 us for the register-shuffle S^T form (round 8) and
// 240 us for the VGPR-clamped variant (round 7). Keep: K/V dbuf, one barrier
// per tile, XCD-local (b,h) in bid&63, ones-MFMA rowsum, exp2 with scale folded
// into Q, swizzled K/V staging.
__global__ __launch_bounds__(256) void attn_fwd(ushort_t* __restrict__ QY,
                                                const ushort_t* __restrict__ K,
                                                const ushort_t* __restrict__ Vt) {
    __shared__ __align__(16) ushort_t Ks[2][64 * 64];    // [buf][kv][d], swizzled
    __shared__ __align__(16) ushort_t Vs[2][64 * 64];    // [buf][d][kv], swizzled
    __shared__ __align__(16) ushort_t Ps[4 * 32 * 72];   // per-wave [q=32][kv=64], stride 72
    const int tid = threadIdx.x;
    const int lane = tid & 63, wave = tid >> 6;
    const int lane15 = lane & 15, quad = lane >> 4;
    const int sw = lane15 & 7;                            // read-side swizzle key
    const int bid = blockIdx.x;
    const int hb = bid & 63, qslot = bid >> 6;
    const int qb = 15 - qslot;
    const int h = hb & 15, b = hb >> 4;
    const int q0 = qb * 128;
    const size_t baseR = (size_t)b * SEQ * CH + h * HSZ;      // +t*CH+d (Q,K,Y)
    const size_t baseV = ((size_t)b * 1024 + h * HSZ) * SEQ;  // +d*SEQ+t (Vt)
    const int rg = lane >> 3, cg = (lane & 7) ^ rg;           // staging swizzle

    short8 qf[2][2];
    #pragma unroll
    for (int mm = 0; mm < 2; mm++) {
        const ushort_t* qp = QY + baseR + (size_t)(q0 + wave * 32 + mm * 16 + lane15) * CH + quad * 8;
        qf[mm][0] = *(const short8*)qp;
        qf[mm][1] = *(const short8*)(qp + 32);
    }
    const short8 kOnes = (short8)(short)0x3F80;  // bf16 1.0 x8

    floatx4 o[2][5];  // [mm][0..3]=O d-chunks, [4]=l (rowsum)
    #pragma unroll
    for (int mm = 0; mm < 2; mm++)
        #pragma unroll
        for (int j = 0; j < 5; j++) o[mm][j] = {0.f, 0.f, 0.f, 0.f};

    const int nkt = 2 * qb + 2;
    // preamble: stage tile 0 into buf 0
    #pragma unroll
    for (int l = wave; l < 8; l += 4) {
        GLD16(K  + baseR + (size_t)(l * 8 + rg) * CH + cg * 8, &Ks[0][l * 512]);
        GLD16(Vt + baseV + (size_t)(l * 8 + rg) * SEQ + cg * 8, &Vs[0][l * 512]);
    }

    for (int kt = 0; kt < nkt; kt++) {
        __syncthreads();  // staging of kt landed; all waves done with buf kt^1
        const int cur = kt & 1;
        if (kt + 1 < nkt) {
            const int kv1 = (kt + 1) * 64, nb = cur ^ 1;
            #pragma unroll
            for (int l = wave; l < 8; l += 4) {
                GLD16(K  + baseR + (size_t)(kv1 + l * 8 + rg) * CH + cg * 8, &Ks[nb][l * 512]);
                GLD16(Vt + baseV + (size_t)(l * 8 + rg) * SEQ + kv1 + cg * 8, &Vs[nb][l * 512]);
            }
        }
        const int kv0 = kt * 64;
        const int masked = (kt >= 2 * qb);
        #pragma unroll
        for (int mm = 0; mm < 2; mm++) {
            floatx4 s4[4];
            #pragma unroll
            for (int j = 0; j < 4; j++) {
                short8 b0 = *(const short8*)&Ks[cur][(j * 16 + lane15) * 64 + ((quad ^ sw) * 8)];
                short8 b1 = *(const short8*)&Ks[cur][(j * 16 + lane15) * 64 + (((quad + 4) ^ sw) * 8)];
                floatx4 z = {0.f, 0.f, 0.f, 0.f};
                z = __builtin_amdgcn_mfma_f32_16x16x32_bf16(qf[mm][0], b0, z, 0, 0, 0);
                z = __builtin_amdgcn_mfma_f32_16x16x32_bf16(qf[mm][1], b1, z, 0, 0, 0);
                s4[j] = z;
            }
            const int qrow_base = q0 + wave * 32 + mm * 16 + quad * 4;
            if (masked) {
                #pragma unroll
                for (int j = 0; j < 4; j++) {
                    const int col = kv0 + j * 16 + lane15;
                    #pragma unroll
                    for (int r = 0; r < 4; r++)
                        s4[j][r] = (col <= qrow_base + r) ? s4[j][r] : -1e30f;
                }
            }
            // p = 2^s  (2^-1e30 -> 0 for masked lanes)
            #pragma unroll
            for (int j = 0; j < 4; j++)
                #pragma unroll
                for (int r = 0; r < 4; r++)
                    Ps[wave * 2304 + (mm * 16 + quad * 4 + r) * 72 + j * 16 + lane15] =
                        f2b(exp2f(s4[j][r]));
        }
        // Ps wave-private: lgkmcnt auto-wait orders write->read, no barrier

        #pragma unroll
        for (int kk = 0; kk < 2; kk++) {
            #pragma unroll
            for (int mm = 0; mm < 2; mm++) {
                short8 a = *(const short8*)&Ps[wave * 2304 + (mm * 16 + lane15) * 72 + kk * 32 + quad * 8];
                #pragma unroll
                for (int jn = 0; jn < 4; jn++) {
                    short8 bb = *(const short8*)&Vs[cur][(jn * 16 + lane15) * 64 + (((kk * 4 + quad) ^ sw) * 8)];
                    o[mm][jn] = __builtin_amdgcn_mfma_f32_16x16x32_bf16(a, bb, o[mm][jn], 0, 0, 0);
                }
                o[mm][4] = __builtin_amdgcn_mfma_f32_16x16x32_bf16(a, kOnes, o[mm][4], 0, 0, 0);
            }
        }
    }

    // epilogue: Y = O / l
    #pragma unroll
    for (int mm = 0; mm < 2; mm++)
        #pragma unroll
        for (int r = 0; r < 4; r++) {
            const int qrow = q0 + wave * 32 + mm * 16 + quad * 4 + r;
            const float rinv = 1.0f / fmaxf(o[mm][4][r], 1e-30f);
            #pragma unroll
            for (int jn = 0; jn < 4; jn++)
                QY[baseR + (size_t)qrow * CH + jn * 16 + lane15] = f2b(o[mm][jn][r] * rinv);
        }
}

extern "C" void kernel_launch(void* const* d_in, const int* in_sizes, int n_in,
                              void* d_out, int out_size, void* d_ws, size_t ws_size,
                              hipStream_t stream) {
    const void* x  = d_in[0];
    const void* Wk = d_in[1];
    const void* bk = d_in[2];
    const void* Wq = d_in[3];
    const void* bq = d_in[4];
    const void* Wv = d_in[5];
    const void* bv = d_in[6];
    const void* Wo = d_in[7];
    const void* bo = d_in[8];

    ushort_t* ws    = (ushort_t*)d_ws;
    int*      flag  = (int*)d_ws;
    ushort_t* biasC = ws + 2048;                    // 4x1024: q,k,v,o (contiguous)
    ushort_t* WqkvT = ws + 32768;                   // 3x1M contiguous: q,k,v
    ushort_t* WoT   = WqkvT + 3u * (1u << 20);
    ushort_t* xb    = ws + 4227072;                 // 8M elems bf16
    ushort_t* Qb    = ws + 12615680;                // 8M elems (becomes Y)
    ushort_t* Kb    = (ushort_t*)d_out;             // d_out scratch until final GEMM
    ushort_t* VtB   = Kb + (size_t)MROWS * CH;

    detect_dtype<<<1, 64, 0, stream>>>((const ushort_t*)x, flag);

    dim3 tgrid(32, 32, 4);
    convert_wt4<<<tgrid, 256, 0, stream>>>(Wq, Wk, Wv, Wo,
                                           WqkvT, WqkvT + (1u << 20), WqkvT + 2u * (1u << 20), WoT, flag);
    convert_bias4<<<16, 256, 0, stream>>>(bq, bk, bv, bo, biasC, flag);
    convert_x<<<MROWS * CH / (256 * 8), 256, 0, stream>>>(x, xb, flag);

    // scale = (1/sqrt(64)) * log2(e), folded into Q so attention uses exp2
    dim3 qgrid(MROWS / 128, 3 * CH / 128);
    gemm_qkv<<<qgrid, 256, 0, stream>>>(xb, WqkvT, biasC, Qb, Kb, VtB, 0.1803368801f);

    attn_fwd<<<dim3(1024), 256, 0, stream>>>(Qb, Kb, VtB);

    dim3 ogrid(MROWS / 128, CH / 128);
    gemm_bt<<<ogrid, 256, 0, stream>>>(Qb, WoT, biasC + 3072, d_out, MROWS, CH, CH, flag);
}